// Round 1
// baseline (1073.066 us; speedup 1.0000x reference)
//
#include <hip/hip_runtime.h>
#include <cmath>

constexpr int T_TOK = 8192;   // B*S
constexpr int DM    = 1024;   // d
constexpr int FF    = 4096;   // f
constexpr int NE    = 8;      // experts
constexpr int KTOP  = 2;
constexpr int CAP   = 2560;   // ceil(1.25 * T*K / E)

typedef _Float16 f16x8 __attribute__((ext_vector_type(8)));
typedef float    f32x4 __attribute__((ext_vector_type(4)));

__device__ __forceinline__ void glds16(const void* g, void* l) {
  __builtin_amdgcn_global_load_lds(
      (const __attribute__((address_space(1))) unsigned int*)g,
      (__attribute__((address_space(3))) unsigned int*)l, 16, 0, 0);
}

// ---------------- router: fp64 logits/softmax/top-2, one wave per token ----------------
__global__ __launch_bounds__(256) void router_kernel(
    const float* __restrict__ x, const float* __restrict__ Wr,
    const float* __restrict__ br, int* __restrict__ topk_e, float* __restrict__ topk_w)
{
  int wave = threadIdx.x >> 6, lane = threadIdx.x & 63;
  int t = blockIdx.x * 4 + wave;
  const float* xr = x + (size_t)t * DM;
  double acc[NE];
#pragma unroll
  for (int e = 0; e < NE; ++e) acc[e] = 0.0;
  for (int j = lane; j < DM; j += 64) {
    double xv = (double)xr[j];
    const float* wr = Wr + (size_t)j * NE;
#pragma unroll
    for (int e = 0; e < NE; ++e) acc[e] += xv * (double)wr[e];
  }
#pragma unroll
  for (int off = 32; off >= 1; off >>= 1) {
#pragma unroll
    for (int e = 0; e < NE; ++e) acc[e] += __shfl_down(acc[e], off, 64);
  }
  if (lane == 0) {
    double mx = -1e300;
#pragma unroll
    for (int e = 0; e < NE; ++e) { acc[e] += (double)br[e]; if (acc[e] > mx) mx = acc[e]; }
    double p[NE]; double s = 0.0;
#pragma unroll
    for (int e = 0; e < NE; ++e) { p[e] = exp(acc[e] - mx); s += p[e]; }
#pragma unroll
    for (int e = 0; e < NE; ++e) p[e] /= s;
    int e1 = 0;
    for (int e = 1; e < NE; ++e) if (p[e] > p[e1]) e1 = e;           // ties -> lowest idx
    int e2 = (e1 == 0) ? 1 : 0;
    for (int e = 0; e < NE; ++e) { if (e == e1) continue; if (p[e] > p[e2]) e2 = e; }
    double wsum = p[e1] + p[e2]; if (wsum < 1e-9) wsum = 1e-9;
    topk_e[t*2+0] = e1; topk_e[t*2+1] = e2;
    topk_w[t*2+0] = (float)(p[e1] / wsum);
    topk_w[t*2+1] = (float)(p[e2] / wsum);
  }
}

// ---------------- FCFS capacity scan: single block, ballot ranks + LDS prefix ----------------
__global__ __launch_bounds__(256) void scan_kernel(
    const int* __restrict__ topk_e, int* __restrict__ assign_slot,
    int* __restrict__ slot_token, int* __restrict__ counts)
{
  __shared__ int base[NE];
  __shared__ int wave_cnt[4][NE];
  __shared__ int wave_base[4][NE];
  int tid = threadIdx.x, lane = tid & 63, wave = tid >> 6;
  if (tid < NE) base[tid] = 0;
  __syncthreads();
  unsigned long long ltmask = (1ull << lane) - 1ull;
  for (int it = 0; it < (T_TOK * KTOP) / 256; ++it) {
    int gi = it * 256 + tid;
    int e = topk_e[gi];
    int rank = 0;
#pragma unroll
    for (int ee = 0; ee < NE; ++ee) {
      unsigned long long m = __ballot(e == ee);
      if (e == ee) rank = __popcll(m & ltmask);
      if (lane == 0) wave_cnt[wave][ee] = __popcll(m);
    }
    __syncthreads();
    if (tid < NE) {
      int b = base[tid];
#pragma unroll
      for (int w = 0; w < 4; ++w) { wave_base[w][tid] = b; b += wave_cnt[w][tid]; }
      base[tid] = b;
    }
    __syncthreads();
    int pos = wave_base[wave][e] + rank;
    bool keep = pos < CAP;
    assign_slot[gi] = keep ? (e * CAP + pos) : -1;
    if (keep) slot_token[e * CAP + pos] = gi >> 1;   // K=2
    __syncthreads();
  }
  if (tid < NE) counts[tid] = base[tid] < CAP ? base[tid] : CAP;
}

// ---------------- fp32 [E][R][C] -> fp16 [E][C][R] (weights to B^T layout) ----------------
__global__ __launch_bounds__(256) void transpose_f16(
    const float* __restrict__ in, _Float16* __restrict__ out, int R, int C)
{
  __shared__ float tile[32][33];
  size_t eoff = (size_t)blockIdx.z * R * C;
  const float* src = in + eoff;
  _Float16* dst = out + eoff;
  int c0 = blockIdx.x * 32, r0 = blockIdx.y * 32;
  int tx = threadIdx.x, ty = threadIdx.y;
#pragma unroll
  for (int i = 0; i < 4; ++i)
    tile[ty + i*8][tx] = src[(size_t)(r0 + ty + i*8) * C + (c0 + tx)];
  __syncthreads();
#pragma unroll
  for (int i = 0; i < 4; ++i)
    dst[(size_t)(c0 + ty + i*8) * R + (r0 + tx)] = (_Float16)tile[tx][ty + i*8];
}

// ---------------- gather kept tokens into [E][CAP][d] fp16 ----------------
__global__ __launch_bounds__(256) void gather_kernel(
    const float* __restrict__ x, const int* __restrict__ slot_token,
    const int* __restrict__ counts, _Float16* __restrict__ xbuf)
{
  int p = blockIdx.x, e = blockIdx.y;
  if (p >= counts[e]) return;
  int tkn = slot_token[e * CAP + p];
  float4 v = ((const float4*)(x + (size_t)tkn * DM))[threadIdx.x];
  _Float16 tmp[4] = {(_Float16)v.x, (_Float16)v.y, (_Float16)v.z, (_Float16)v.w};
  uint2 bits; __builtin_memcpy(&bits, tmp, 8);
  ((uint2*)(xbuf + ((size_t)e * CAP + p) * DM))[threadIdx.x] = bits;
}

// ---------------- m97-style fp16 MFMA GEMM: C[e] = act(A[e] @ Bt[e]^T + bias[e]) ----------------
// A: [NE][CAP][K], Bt: [NE][N][K], C: [NE][CAP][N]; tiles past counts[e] early-exit.
template <bool GELU, bool OUTF16>
__global__ __launch_bounds__(256) void gemm_bt(
    const _Float16* __restrict__ A, const _Float16* __restrict__ Bt,
    const float* __restrict__ bias, void* __restrict__ Cout,
    const int* __restrict__ counts, int K, int N)
{
  constexpr int BM = 128, BN = 128, BK = 64;
  __shared__ _Float16 As[BM * BK];
  __shared__ _Float16 Bs[BN * BK];
  int e = blockIdx.z;
  int Me = counts[e];
  int m0 = blockIdx.y * BM;
  if (m0 >= Me) return;               // capacity padding: skip empty tiles
  int tid = threadIdx.x, lane = tid & 63, wave = tid >> 6;
  int wm = wave >> 1, wn = wave & 1;  // 2x2 waves, 64x64 per wave
  const _Float16* Ae = A + ((size_t)e * CAP + m0) * K;
  const _Float16* Be = Bt + ((size_t)e * N + (size_t)blockIdx.x * BN) * K;
  int ldrow = tid >> 3;               // 32 rows per round, 8 lanes x 16B per row
  int ldcol = (tid & 7) * 8;
  f32x4 acc[4][4] = {};
  for (int k0 = 0; k0 < K; k0 += BK) {
#pragma unroll
    for (int r = 0; r < 4; ++r) {
      glds16(Ae + (size_t)(r*32 + ldrow) * K + (k0 + ldcol), (char*)As + (r*4096 + wave*1024));
      glds16(Be + (size_t)(r*32 + ldrow) * K + (k0 + ldcol), (char*)Bs + (r*4096 + wave*1024));
    }
    __syncthreads();
    int quad = lane >> 4, low = lane & 15;
#pragma unroll
    for (int kk = 0; kk < BK; kk += 32) {
      f16x8 af[4], bf[4];
#pragma unroll
      for (int mi = 0; mi < 4; ++mi)
        af[mi] = *(const f16x8*)(As + (wm*64 + mi*16 + low) * BK + kk + quad*8);
#pragma unroll
      for (int ni = 0; ni < 4; ++ni)
        bf[ni] = *(const f16x8*)(Bs + (wn*64 + ni*16 + low) * BK + kk + quad*8);
#pragma unroll
      for (int mi = 0; mi < 4; ++mi)
#pragma unroll
        for (int ni = 0; ni < 4; ++ni)
          acc[mi][ni] = __builtin_amdgcn_mfma_f32_16x16x32_f16(af[mi], bf[ni], acc[mi][ni], 0, 0, 0);
    }
    __syncthreads();
  }
  int quad = lane >> 4, low = lane & 15;
  const float* be = bias + (size_t)e * N;
#pragma unroll
  for (int mi = 0; mi < 4; ++mi) {
#pragma unroll
    for (int r = 0; r < 4; ++r) {
      int row = m0 + wm*64 + mi*16 + quad*4 + r;      // C/D: row=(lane>>4)*4+reg, col=lane&15
      size_t rowoff = ((size_t)e * CAP + row) * N;
#pragma unroll
      for (int ni = 0; ni < 4; ++ni) {
        int col = blockIdx.x * BN + wn*64 + ni*16 + low;
        float v = acc[mi][ni][r] + be[col];
        if constexpr (GELU) v = 0.5f * v * (1.0f + erff(v * 0.7071067811865476f));
        if constexpr (OUTF16) ((_Float16*)Cout)[rowoff + col] = (_Float16)v;
        else                  ((float*)Cout)[rowoff + col] = v;
      }
    }
  }
}

// ---------------- combine: out[t] = sum_k w_k * ybuf[slot_k] ----------------
__global__ __launch_bounds__(256) void combine_kernel(
    const float* __restrict__ ybuf, const int* __restrict__ assign_slot,
    const float* __restrict__ topk_w, float* __restrict__ out)
{
  int t = blockIdx.x;
  int s0 = assign_slot[t*2+0], s1 = assign_slot[t*2+1];
  float w0 = topk_w[t*2+0], w1 = topk_w[t*2+1];
  float4 a = {0.f, 0.f, 0.f, 0.f};
  int j = threadIdx.x;
  if (s0 >= 0) {
    float4 y = ((const float4*)(ybuf + (size_t)s0 * DM))[j];
    a.x += w0*y.x; a.y += w0*y.y; a.z += w0*y.z; a.w += w0*y.w;
  }
  if (s1 >= 0) {
    float4 y = ((const float4*)(ybuf + (size_t)s1 * DM))[j];
    a.x += w1*y.x; a.y += w1*y.y; a.z += w1*y.z; a.w += w1*y.w;
  }
  ((float4*)(out + (size_t)t * DM))[j] = a;
}

extern "C" void kernel_launch(void* const* d_in, const int* in_sizes, int n_in,
                              void* d_out, int out_size, void* d_ws, size_t ws_size,
                              hipStream_t stream)
{
  (void)in_sizes; (void)n_in; (void)out_size; (void)ws_size;
  const float* x  = (const float*)d_in[0];
  const float* Wr = (const float*)d_in[1];
  const float* br = (const float*)d_in[2];
  const float* W1 = (const float*)d_in[3];
  const float* b1 = (const float*)d_in[4];
  const float* W2 = (const float*)d_in[5];
  const float* b2 = (const float*)d_in[6];
  float* out = (float*)d_out;

  char* wsp = (char*)d_ws;
  size_t off = 0;
  auto take = [&](size_t bytes) { char* p = wsp + off; off += (bytes + 255) & ~(size_t)255; return p; };
  _Float16* W1t  = (_Float16*)take((size_t)NE * FF * DM * 2);   // [E][f][d]
  _Float16* W2t  = (_Float16*)take((size_t)NE * DM * FF * 2);   // [E][d][f]
  _Float16* xbuf = (_Float16*)take((size_t)NE * CAP * DM * 2);  // [E][cap][d]
  _Float16* hbuf = (_Float16*)take((size_t)NE * CAP * FF * 2);  // [E][cap][f]
  float*    ybuf = (float*)take((size_t)NE * CAP * DM * 4);     // [E][cap][d]
  int*   topk_e      = (int*)take((size_t)T_TOK * KTOP * 4);
  float* topk_w      = (float*)take((size_t)T_TOK * KTOP * 4);
  int*   assign_slot = (int*)take((size_t)T_TOK * KTOP * 4);
  int*   slot_token  = (int*)take((size_t)NE * CAP * 4);
  int*   counts      = (int*)take((size_t)NE * 4);

  router_kernel<<<T_TOK / 4, 256, 0, stream>>>(x, Wr, br, topk_e, topk_w);
  scan_kernel<<<1, 256, 0, stream>>>(topk_e, assign_slot, slot_token, counts);
  transpose_f16<<<dim3(FF/32, DM/32, NE), dim3(32, 8), 0, stream>>>(W1, W1t, DM, FF);
  transpose_f16<<<dim3(DM/32, FF/32, NE), dim3(32, 8), 0, stream>>>(W2, W2t, FF, DM);
  gather_kernel<<<dim3(CAP, NE), 256, 0, stream>>>(x, slot_token, counts, xbuf);
  gemm_bt<true,  true ><<<dim3(FF/128, CAP/128, NE), 256, 0, stream>>>(xbuf, W1t, b1, (void*)hbuf, counts, DM, FF);
  gemm_bt<false, false><<<dim3(DM/128, CAP/128, NE), 256, 0, stream>>>(hbuf, W2t, b2, (void*)ybuf, counts, FF, DM);
  combine_kernel<<<T_TOK, 256, 0, stream>>>(ybuf, assign_slot, topk_w, out);
}

// Round 2
// 882.057 us; speedup vs baseline: 1.2165x; 1.2165x over previous
//
#include <hip/hip_runtime.h>
#include <cmath>

constexpr int T_TOK = 8192;   // B*S
constexpr int DM    = 1024;   // d
constexpr int FF    = 4096;   // f
constexpr int NE    = 8;      // experts
constexpr int KTOP  = 2;
constexpr int CAP   = 2560;   // ceil(1.25 * T*K / E)
constexpr int NCHUNK = (T_TOK * KTOP) / 256;   // 64 chunks for the FCFS scan

typedef _Float16 f16x8 __attribute__((ext_vector_type(8)));
typedef float    f32x4 __attribute__((ext_vector_type(4)));

__device__ __forceinline__ void glds16(const void* g, void* l) {
  __builtin_amdgcn_global_load_lds(
      (const __attribute__((address_space(1))) unsigned int*)g,
      (__attribute__((address_space(3))) unsigned int*)l, 16, 0, 0);
}

// tanh-form GELU: one v_exp_f32, overflow-safe (t=inf -> th=1), max dev ~2e-4
__device__ __forceinline__ float fast_gelu(float v) {
  float u = v * (0.7978845608f + 0.0356774081f * v * v);
  float t = __expf(2.0f * u);
  float th = 1.0f - 2.0f / (t + 1.0f);
  return 0.5f * v * (1.0f + th);
}

// ---------------- router: fp64 logits/softmax/top-2, one wave per token ----------------
__global__ __launch_bounds__(256) void router_kernel(
    const float* __restrict__ x, const float* __restrict__ Wr,
    const float* __restrict__ br, int* __restrict__ topk_e, float* __restrict__ topk_w)
{
  int wave = threadIdx.x >> 6, lane = threadIdx.x & 63;
  int t = blockIdx.x * 4 + wave;
  const float* xr = x + (size_t)t * DM;
  double acc[NE];
#pragma unroll
  for (int e = 0; e < NE; ++e) acc[e] = 0.0;
  for (int j = lane; j < DM; j += 64) {
    double xv = (double)xr[j];
    const float* wr = Wr + (size_t)j * NE;
#pragma unroll
    for (int e = 0; e < NE; ++e) acc[e] += xv * (double)wr[e];
  }
#pragma unroll
  for (int off = 32; off >= 1; off >>= 1) {
#pragma unroll
    for (int e = 0; e < NE; ++e) acc[e] += __shfl_down(acc[e], off, 64);
  }
  if (lane == 0) {
    double mx = -1e300;
#pragma unroll
    for (int e = 0; e < NE; ++e) { acc[e] += (double)br[e]; if (acc[e] > mx) mx = acc[e]; }
    double p[NE]; double s = 0.0;
#pragma unroll
    for (int e = 0; e < NE; ++e) { p[e] = exp(acc[e] - mx); s += p[e]; }
#pragma unroll
    for (int e = 0; e < NE; ++e) p[e] /= s;
    int e1 = 0;
    for (int e = 1; e < NE; ++e) if (p[e] > p[e1]) e1 = e;           // ties -> lowest idx
    int e2 = (e1 == 0) ? 1 : 0;
    for (int e = 0; e < NE; ++e) { if (e == e1) continue; if (p[e] > p[e2]) e2 = e; }
    double wsum = p[e1] + p[e2]; if (wsum < 1e-9) wsum = 1e-9;
    topk_e[t*2+0] = e1; topk_e[t*2+1] = e2;
    topk_w[t*2+0] = (float)(p[e1] / wsum);
    topk_w[t*2+1] = (float)(p[e2] / wsum);
  }
}

// ---------------- FCFS capacity scan, parallel 3-phase ----------------
// phase A: per-chunk expert histogram (ballot-based)
__global__ __launch_bounds__(256) void hist_kernel(
    const int* __restrict__ topk_e, int* __restrict__ hist)   // hist[NCHUNK][NE]
{
  __shared__ int wcnt[4][NE];
  int tid = threadIdx.x, lane = tid & 63, wave = tid >> 6;
  int e = topk_e[blockIdx.x * 256 + tid];
#pragma unroll
  for (int ee = 0; ee < NE; ++ee) {
    unsigned long long m = __ballot(e == ee);
    if (lane == 0) wcnt[wave][ee] = __popcll(m);
  }
  __syncthreads();
  if (tid < NE)
    hist[blockIdx.x * NE + tid] = wcnt[0][tid] + wcnt[1][tid] + wcnt[2][tid] + wcnt[3][tid];
}

// phase B: exclusive prefix over chunks, per expert (8 threads, loads unrolled up-front)
__global__ __launch_bounds__(64) void prefix_kernel(
    const int* __restrict__ hist, int* __restrict__ base, int* __restrict__ counts)
{
  int e = threadIdx.x;
  if (e >= NE) return;
  int h[NCHUNK];
#pragma unroll
  for (int c = 0; c < NCHUNK; ++c) h[c] = hist[c * NE + e];
  int b = 0;
#pragma unroll
  for (int c = 0; c < NCHUNK; ++c) { base[c * NE + e] = b; b += h[c]; }
  counts[e] = b < CAP ? b : CAP;
}

// phase C: recompute ranks, add chunk base, emit slots
__global__ __launch_bounds__(256) void assign_kernel(
    const int* __restrict__ topk_e, const int* __restrict__ base,
    int* __restrict__ assign_slot, int* __restrict__ slot_token)
{
  __shared__ int wcnt[4][NE];
  __shared__ int woff[4][NE];
  int tid = threadIdx.x, lane = tid & 63, wave = tid >> 6;
  int gi = blockIdx.x * 256 + tid;
  int e = topk_e[gi];
  int rank = 0;
  unsigned long long lt = (1ull << lane) - 1ull;
#pragma unroll
  for (int ee = 0; ee < NE; ++ee) {
    unsigned long long m = __ballot(e == ee);
    if (e == ee) rank = __popcll(m & lt);
    if (lane == 0) wcnt[wave][ee] = __popcll(m);
  }
  __syncthreads();
  if (tid < NE) {
    int b = base[blockIdx.x * NE + tid];
#pragma unroll
    for (int w = 0; w < 4; ++w) { woff[w][tid] = b; b += wcnt[w][tid]; }
  }
  __syncthreads();
  int pos = woff[wave][e] + rank;
  bool keep = pos < CAP;
  assign_slot[gi] = keep ? (e * CAP + pos) : -1;
  if (keep) slot_token[e * CAP + pos] = gi >> 1;   // K=2
}

// ---------------- fp32 [E][R][C] -> fp16 [E][C][R] (weights to B^T layout) ----------------
__global__ __launch_bounds__(256) void transpose_f16(
    const float* __restrict__ in, _Float16* __restrict__ out, int R, int C)
{
  __shared__ float tile[32][33];
  size_t eoff = (size_t)blockIdx.z * R * C;
  const float* src = in + eoff;
  _Float16* dst = out + eoff;
  int c0 = blockIdx.x * 32, r0 = blockIdx.y * 32;
  int tx = threadIdx.x, ty = threadIdx.y;
#pragma unroll
  for (int i = 0; i < 4; ++i)
    tile[ty + i*8][tx] = src[(size_t)(r0 + ty + i*8) * C + (c0 + tx)];
  __syncthreads();
#pragma unroll
  for (int i = 0; i < 4; ++i)
    dst[(size_t)(c0 + ty + i*8) * R + (r0 + tx)] = (_Float16)tile[tx][ty + i*8];
}

// ---------------- gather kept tokens into [E][CAP][d] fp16 ----------------
__global__ __launch_bounds__(256) void gather_kernel(
    const float* __restrict__ x, const int* __restrict__ slot_token,
    const int* __restrict__ counts, _Float16* __restrict__ xbuf)
{
  int p = blockIdx.x, e = blockIdx.y;
  if (p >= counts[e]) return;
  int tkn = slot_token[e * CAP + p];
  float4 v = ((const float4*)(x + (size_t)tkn * DM))[threadIdx.x];
  _Float16 tmp[4] = {(_Float16)v.x, (_Float16)v.y, (_Float16)v.z, (_Float16)v.w};
  uint2 bits; __builtin_memcpy(&bits, tmp, 8);
  ((uint2*)(xbuf + ((size_t)e * CAP + p) * DM))[threadIdx.x] = bits;
}

// ---------------- fp16 MFMA GEMM with XOR-swizzled LDS ----------------
// A: [NE][CAP][K], Bt: [NE][N][K], C: [NE][CAP][N]; tiles past counts[e] early-exit.
// LDS layout: 16B chunk c of row r stored at chunk position (c ^ (r&7)) -> bank-conflict-free
// ds_read_b128 fragment loads. Swizzle is applied on the GLOBAL address side of
// global_load_lds (lane->LDS mapping is fixed: uniform base + lane*16).
template <bool GELU, bool OUTF16>
__global__ __launch_bounds__(256) void gemm_bt(
    const _Float16* __restrict__ A, const _Float16* __restrict__ Bt,
    const float* __restrict__ bias, void* __restrict__ Cout,
    const int* __restrict__ counts, int K, int N)
{
  constexpr int BM = 128, BN = 128, BK = 64;
  __shared__ _Float16 As[BM * BK];
  __shared__ _Float16 Bs[BN * BK];
  int e = blockIdx.z;
  int Me = counts[e];
  int m0 = blockIdx.y * BM;
  if (m0 >= Me) return;               // capacity padding: skip empty tiles
  int tid = threadIdx.x, lane = tid & 63, wave = tid >> 6;
  int wm = wave >> 1, wn = wave & 1;  // 2x2 waves, 64x64 per wave
  const _Float16* Ae = A + ((size_t)e * CAP + m0) * K;
  const _Float16* Be = Bt + ((size_t)e * N + (size_t)blockIdx.x * BN) * K;
  int ldrow = tid >> 3;                                   // 32 rows per round
  int ldcol = (((tid & 7) ^ ((tid >> 3) & 7)) * 8);       // XOR-swizzled 16B chunk
  f32x4 acc[4][4] = {};
  for (int k0 = 0; k0 < K; k0 += BK) {
#pragma unroll
    for (int r = 0; r < 4; ++r) {
      glds16(Ae + (size_t)(r*32 + ldrow) * K + (k0 + ldcol), (char*)As + (r*4096 + wave*1024));
      glds16(Be + (size_t)(r*32 + ldrow) * K + (k0 + ldcol), (char*)Bs + (r*4096 + wave*1024));
    }
    __syncthreads();
    int quad = lane >> 4, low = lane & 15, swz = low & 7;
    const _Float16* Abase = As + (size_t)(wm*64 + low) * BK;
    const _Float16* Bbase = Bs + (size_t)(wn*64 + low) * BK;
#pragma unroll
    for (int kk = 0; kk < BK; kk += 32) {
      int c = (kk >> 3) + quad;                  // logical 16B chunk within row
      int coff = ((c ^ swz) << 3);               // swizzled element offset
      f16x8 af[4], bf[4];
#pragma unroll
      for (int mi = 0; mi < 4; ++mi)
        af[mi] = *(const f16x8*)(Abase + mi*16*BK + coff);
#pragma unroll
      for (int ni = 0; ni < 4; ++ni)
        bf[ni] = *(const f16x8*)(Bbase + ni*16*BK + coff);
#pragma unroll
      for (int mi = 0; mi < 4; ++mi)
#pragma unroll
        for (int ni = 0; ni < 4; ++ni)
          acc[mi][ni] = __builtin_amdgcn_mfma_f32_16x16x32_f16(af[mi], bf[ni], acc[mi][ni], 0, 0, 0);
    }
    __syncthreads();
  }
  int quad = lane >> 4, low = lane & 15;
  const float* be = bias + (size_t)e * N;
#pragma unroll
  for (int mi = 0; mi < 4; ++mi) {
#pragma unroll
    for (int r = 0; r < 4; ++r) {
      int row = m0 + wm*64 + mi*16 + quad*4 + r;      // C/D: row=(lane>>4)*4+reg, col=lane&15
      size_t rowoff = ((size_t)e * CAP + row) * N;
#pragma unroll
      for (int ni = 0; ni < 4; ++ni) {
        int col = blockIdx.x * BN + wn*64 + ni*16 + low;
        float v = acc[mi][ni][r] + be[col];
        if constexpr (GELU) v = fast_gelu(v);
        if constexpr (OUTF16) ((_Float16*)Cout)[rowoff + col] = (_Float16)v;
        else                  ((float*)Cout)[rowoff + col] = v;
      }
    }
  }
}

// ---------------- combine: out[t] = sum_k w_k * ybuf[slot_k] ----------------
__global__ __launch_bounds__(256) void combine_kernel(
    const float* __restrict__ ybuf, const int* __restrict__ assign_slot,
    const float* __restrict__ topk_w, float* __restrict__ out)
{
  int t = blockIdx.x;
  int s0 = assign_slot[t*2+0], s1 = assign_slot[t*2+1];
  float w0 = topk_w[t*2+0], w1 = topk_w[t*2+1];
  float4 a = {0.f, 0.f, 0.f, 0.f};
  int j = threadIdx.x;
  if (s0 >= 0) {
    float4 y = ((const float4*)(ybuf + (size_t)s0 * DM))[j];
    a.x += w0*y.x; a.y += w0*y.y; a.z += w0*y.z; a.w += w0*y.w;
  }
  if (s1 >= 0) {
    float4 y = ((const float4*)(ybuf + (size_t)s1 * DM))[j];
    a.x += w1*y.x; a.y += w1*y.y; a.z += w1*y.z; a.w += w1*y.w;
  }
  ((float4*)(out + (size_t)t * DM))[j] = a;
}

extern "C" void kernel_launch(void* const* d_in, const int* in_sizes, int n_in,
                              void* d_out, int out_size, void* d_ws, size_t ws_size,
                              hipStream_t stream)
{
  (void)in_sizes; (void)n_in; (void)out_size; (void)ws_size;
  const float* x  = (const float*)d_in[0];
  const float* Wr = (const float*)d_in[1];
  const float* br = (const float*)d_in[2];
  const float* W1 = (const float*)d_in[3];
  const float* b1 = (const float*)d_in[4];
  const float* W2 = (const float*)d_in[5];
  const float* b2 = (const float*)d_in[6];
  float* out = (float*)d_out;

  char* wsp = (char*)d_ws;
  size_t off = 0;
  auto take = [&](size_t bytes) { char* p = wsp + off; off += (bytes + 255) & ~(size_t)255; return p; };
  _Float16* W1t  = (_Float16*)take((size_t)NE * FF * DM * 2);   // [E][f][d]
  _Float16* W2t  = (_Float16*)take((size_t)NE * DM * FF * 2);   // [E][d][f]
  _Float16* xbuf = (_Float16*)take((size_t)NE * CAP * DM * 2);  // [E][cap][d]
  _Float16* hbuf = (_Float16*)take((size_t)NE * CAP * FF * 2);  // [E][cap][f]
  float*    ybuf = (float*)take((size_t)NE * CAP * DM * 4);     // [E][cap][d]
  int*   topk_e      = (int*)take((size_t)T_TOK * KTOP * 4);
  float* topk_w      = (float*)take((size_t)T_TOK * KTOP * 4);
  int*   assign_slot = (int*)take((size_t)T_TOK * KTOP * 4);
  int*   slot_token  = (int*)take((size_t)NE * CAP * 4);
  int*   counts      = (int*)take((size_t)NE * 4);
  int*   hist        = (int*)take((size_t)NCHUNK * NE * 4);
  int*   cbase       = (int*)take((size_t)NCHUNK * NE * 4);

  router_kernel<<<T_TOK / 4, 256, 0, stream>>>(x, Wr, br, topk_e, topk_w);
  hist_kernel<<<NCHUNK, 256, 0, stream>>>(topk_e, hist);
  prefix_kernel<<<1, 64, 0, stream>>>(hist, cbase, counts);
  assign_kernel<<<NCHUNK, 256, 0, stream>>>(topk_e, cbase, assign_slot, slot_token);
  transpose_f16<<<dim3(FF/32, DM/32, NE), dim3(32, 8), 0, stream>>>(W1, W1t, DM, FF);
  transpose_f16<<<dim3(DM/32, FF/32, NE), dim3(32, 8), 0, stream>>>(W2, W2t, FF, DM);
  gather_kernel<<<dim3(CAP, NE), 256, 0, stream>>>(x, slot_token, counts, xbuf);
  gemm_bt<true,  true ><<<dim3(FF/128, CAP/128, NE), 256, 0, stream>>>(xbuf, W1t, b1, (void*)hbuf, counts, DM, FF);
  gemm_bt<false, false><<<dim3(DM/128, CAP/128, NE), 256, 0, stream>>>(hbuf, W2t, b2, (void*)ybuf, counts, FF, DM);
  combine_kernel<<<T_TOK, 256, 0, stream>>>(ybuf, assign_slot, topk_w, out);
}

// Round 3
// 815.497 us; speedup vs baseline: 1.3158x; 1.0816x over previous
//
#include <hip/hip_runtime.h>
#include <cmath>

constexpr int T_TOK = 8192;   // B*S
constexpr int DM    = 1024;   // d
constexpr int FF    = 4096;   // f
constexpr int NE    = 8;      // experts
constexpr int KTOP  = 2;
constexpr int CAP   = 2560;   // ceil(1.25 * T*K / E)
constexpr int NCHUNK = (T_TOK * KTOP) / 256;   // 64 chunks for the FCFS scan

typedef _Float16 f16x8  __attribute__((ext_vector_type(8)));
typedef float    f32x16 __attribute__((ext_vector_type(16)));

__device__ __forceinline__ void glds16(const void* g, void* l) {
  __builtin_amdgcn_global_load_lds(
      (const __attribute__((address_space(1))) unsigned int*)g,
      (__attribute__((address_space(3))) unsigned int*)l, 16, 0, 0);
}

// tanh-form GELU: one v_exp_f32, overflow-safe (t=inf -> th=1), max dev ~2e-4
__device__ __forceinline__ float fast_gelu(float v) {
  float u = v * (0.7978845608f + 0.0356774081f * v * v);
  float t = __expf(2.0f * u);
  float th = 1.0f - 2.0f / (t + 1.0f);
  return 0.5f * v * (1.0f + th);
}

// ---------------- router: fp64 logits/softmax/top-2, one wave per token ----------------
__global__ __launch_bounds__(256) void router_kernel(
    const float* __restrict__ x, const float* __restrict__ Wr,
    const float* __restrict__ br, int* __restrict__ topk_e, float* __restrict__ topk_w)
{
  int wave = threadIdx.x >> 6, lane = threadIdx.x & 63;
  int t = blockIdx.x * 4 + wave;
  const float4* xr4 = (const float4*)(x + (size_t)t * DM);
  double acc[NE];
#pragma unroll
  for (int e = 0; e < NE; ++e) acc[e] = 0.0;
#pragma unroll
  for (int it = 0; it < DM / 4 / 64; ++it) {
    int j4 = it * 64 + lane;
    float4 xv = xr4[j4];
    const float* wr = Wr + (size_t)j4 * 4 * NE;
    float xs[4] = {xv.x, xv.y, xv.z, xv.w};
#pragma unroll
    for (int s = 0; s < 4; ++s) {
      double xd = (double)xs[s];
#pragma unroll
      for (int e = 0; e < NE; ++e) acc[e] += xd * (double)wr[s * NE + e];
    }
  }
#pragma unroll
  for (int off = 32; off >= 1; off >>= 1) {
#pragma unroll
    for (int e = 0; e < NE; ++e) acc[e] += __shfl_down(acc[e], off, 64);
  }
  if (lane == 0) {
    double mx = -1e300;
#pragma unroll
    for (int e = 0; e < NE; ++e) { acc[e] += (double)br[e]; if (acc[e] > mx) mx = acc[e]; }
    double p[NE]; double s = 0.0;
#pragma unroll
    for (int e = 0; e < NE; ++e) { p[e] = exp(acc[e] - mx); s += p[e]; }
#pragma unroll
    for (int e = 0; e < NE; ++e) p[e] /= s;
    int e1 = 0;
    for (int e = 1; e < NE; ++e) if (p[e] > p[e1]) e1 = e;           // ties -> lowest idx
    int e2 = (e1 == 0) ? 1 : 0;
    for (int e = 0; e < NE; ++e) { if (e == e1) continue; if (p[e] > p[e2]) e2 = e; }
    double wsum = p[e1] + p[e2]; if (wsum < 1e-9) wsum = 1e-9;
    topk_e[t*2+0] = e1; topk_e[t*2+1] = e2;
    topk_w[t*2+0] = (float)(p[e1] / wsum);
    topk_w[t*2+1] = (float)(p[e2] / wsum);
  }
}

// ---------------- FCFS capacity scan, parallel 3-phase ----------------
__global__ __launch_bounds__(256) void hist_kernel(
    const int* __restrict__ topk_e, int* __restrict__ hist)   // hist[NCHUNK][NE]
{
  __shared__ int wcnt[4][NE];
  int tid = threadIdx.x, lane = tid & 63, wave = tid >> 6;
  int e = topk_e[blockIdx.x * 256 + tid];
#pragma unroll
  for (int ee = 0; ee < NE; ++ee) {
    unsigned long long m = __ballot(e == ee);
    if (lane == 0) wcnt[wave][ee] = __popcll(m);
  }
  __syncthreads();
  if (tid < NE)
    hist[blockIdx.x * NE + tid] = wcnt[0][tid] + wcnt[1][tid] + wcnt[2][tid] + wcnt[3][tid];
}

__global__ __launch_bounds__(64) void prefix_kernel(
    const int* __restrict__ hist, int* __restrict__ base, int* __restrict__ counts)
{
  int e = threadIdx.x;
  if (e >= NE) return;
  int h[NCHUNK];
#pragma unroll
  for (int c = 0; c < NCHUNK; ++c) h[c] = hist[c * NE + e];
  int b = 0;
#pragma unroll
  for (int c = 0; c < NCHUNK; ++c) { base[c * NE + e] = b; b += h[c]; }
  counts[e] = b < CAP ? b : CAP;
}

__global__ __launch_bounds__(256) void assign_kernel(
    const int* __restrict__ topk_e, const int* __restrict__ base,
    int* __restrict__ assign_slot, int* __restrict__ slot_token)
{
  __shared__ int wcnt[4][NE];
  __shared__ int woff[4][NE];
  int tid = threadIdx.x, lane = tid & 63, wave = tid >> 6;
  int gi = blockIdx.x * 256 + tid;
  int e = topk_e[gi];
  int rank = 0;
  unsigned long long lt = (1ull << lane) - 1ull;
#pragma unroll
  for (int ee = 0; ee < NE; ++ee) {
    unsigned long long m = __ballot(e == ee);
    if (e == ee) rank = __popcll(m & lt);
    if (lane == 0) wcnt[wave][ee] = __popcll(m);
  }
  __syncthreads();
  if (tid < NE) {
    int b = base[blockIdx.x * NE + tid];
#pragma unroll
    for (int w = 0; w < 4; ++w) { woff[w][tid] = b; b += wcnt[w][tid]; }
  }
  __syncthreads();
  int pos = woff[wave][e] + rank;
  bool keep = pos < CAP;
  assign_slot[gi] = keep ? (e * CAP + pos) : -1;
  if (keep) slot_token[e * CAP + pos] = gi >> 1;   // K=2
}

// ---------------- fp32 [E][R][C] -> fp16 [E][C][R], 64x64 tiles, 16B I/O both sides ----------------
__global__ __launch_bounds__(256) void transpose_f16(
    const float* __restrict__ in, _Float16* __restrict__ out, int R, int C)
{
  __shared__ float tile[64][65];
  size_t eoff = (size_t)blockIdx.z * R * C;
  const float* src = in + eoff;
  _Float16* dst = out + eoff;
  int r0 = blockIdx.y * 64, c0 = blockIdx.x * 64;
  int t = threadIdx.x;
  int rr = t >> 4, cc = (t & 15) * 4;          // 16 in-rows per pass, float4 each
#pragma unroll
  for (int i = 0; i < 4; ++i) {
    float4 v = *(const float4*)(src + (size_t)(r0 + rr + i*16) * C + (c0 + cc));
    tile[rr + i*16][cc + 0] = v.x; tile[rr + i*16][cc + 1] = v.y;
    tile[rr + i*16][cc + 2] = v.z; tile[rr + i*16][cc + 3] = v.w;
  }
  __syncthreads();
  int oc = t >> 3, orr = (t & 7) * 8;          // 32 out-rows per pass, 8 fp16 each
#pragma unroll
  for (int i = 0; i < 2; ++i) {
    int c = oc + i * 32;
    _Float16 tmp[8];
#pragma unroll
    for (int j = 0; j < 8; ++j) tmp[j] = (_Float16)tile[orr + j][c];
    *(uint4*)(dst + (size_t)(c0 + c) * R + (r0 + orr)) = *(uint4*)tmp;
  }
}

// ---------------- gather kept tokens into [E][CAP][d] fp16 ----------------
__global__ __launch_bounds__(256) void gather_kernel(
    const float* __restrict__ x, const int* __restrict__ slot_token,
    const int* __restrict__ counts, _Float16* __restrict__ xbuf)
{
  int p = blockIdx.x, e = blockIdx.y;
  if (p >= counts[e]) return;
  int tkn = slot_token[e * CAP + p];
  float4 v = ((const float4*)(x + (size_t)tkn * DM))[threadIdx.x];
  _Float16 tmp[4] = {(_Float16)v.x, (_Float16)v.y, (_Float16)v.z, (_Float16)v.w};
  uint2 bits; __builtin_memcpy(&bits, tmp, 8);
  ((uint2*)(xbuf + ((size_t)e * CAP + p) * DM))[threadIdx.x] = bits;
}

// ---------------- fp16 MFMA GEMM, 32x32x16, XOR-swizzled LDS ----------------
// A: [NE][CAP][K], Bt: [NE][N][K], C: [NE][CAP][N]; tiles past counts[e] early-exit.
// LDS: 16B chunk c of row r stored at chunk (c ^ (r&7)); swizzle applied on the
// global side of global_load_lds, inverted on ds_read_b128 fragment loads.
// 32x32x16 layouts: A/B: m|n=lane&31, k=(lane>>5)*8+j; C/D: col=lane&31,
// row=(reg&3)+8*(reg>>2)+4*(lane>>5).
template <bool GELU, bool OUTF16>
__global__ __launch_bounds__(256, 3) void gemm_bt(
    const _Float16* __restrict__ A, const _Float16* __restrict__ Bt,
    const float* __restrict__ bias, void* __restrict__ Cout,
    const int* __restrict__ counts, int K, int N)
{
  constexpr int BM = 128, BN = 128, BK = 64;
  __shared__ _Float16 As[BM * BK];
  __shared__ _Float16 Bs[BN * BK];
  int e = blockIdx.z;
  int Me = counts[e];
  int m0 = blockIdx.y * BM;
  if (m0 >= Me) return;               // capacity padding: skip empty tiles
  int tid = threadIdx.x, lane = tid & 63, wave = tid >> 6;
  int wm = wave >> 1, wn = wave & 1;  // 2x2 waves, 64x64 per wave
  const _Float16* Ae = A + ((size_t)e * CAP + m0) * K;
  const _Float16* Be = Bt + ((size_t)e * N + (size_t)blockIdx.x * BN) * K;
  int ldrow = tid >> 3;                                   // 32 rows per round
  int ldcol = (((tid & 7) ^ ((tid >> 3) & 7)) * 8);       // XOR-swizzled 16B chunk
  int n31 = lane & 31, khalf = lane >> 5, swz = lane & 7;
  f32x16 acc[2][2] = {};
  for (int k0 = 0; k0 < K; k0 += BK) {
#pragma unroll
    for (int r = 0; r < 4; ++r) {
      glds16(Ae + (size_t)(r*32 + ldrow) * K + (k0 + ldcol), (char*)As + (r*4096 + wave*1024));
      glds16(Be + (size_t)(r*32 + ldrow) * K + (k0 + ldcol), (char*)Bs + (r*4096 + wave*1024));
    }
    __syncthreads();
    const _Float16* Ab = As + (size_t)(wm*64 + n31) * BK;
    const _Float16* Bb = Bs + (size_t)(wn*64 + n31) * BK;
#pragma unroll
    for (int kk = 0; kk < 4; ++kk) {             // 16-k steps
      int c = kk * 2 + khalf;                    // logical 16B chunk within row
      int coff = ((c ^ swz) << 3);               // swizzled element offset
      f16x8 a0 = *(const f16x8*)(Ab + coff);
      f16x8 a1 = *(const f16x8*)(Ab + 32*BK + coff);
      f16x8 b0 = *(const f16x8*)(Bb + coff);
      f16x8 b1 = *(const f16x8*)(Bb + 32*BK + coff);
      acc[0][0] = __builtin_amdgcn_mfma_f32_32x32x16_f16(a0, b0, acc[0][0], 0, 0, 0);
      acc[0][1] = __builtin_amdgcn_mfma_f32_32x32x16_f16(a0, b1, acc[0][1], 0, 0, 0);
      acc[1][0] = __builtin_amdgcn_mfma_f32_32x32x16_f16(a1, b0, acc[1][0], 0, 0, 0);
      acc[1][1] = __builtin_amdgcn_mfma_f32_32x32x16_f16(a1, b1, acc[1][1], 0, 0, 0);
    }
    __syncthreads();
  }
  const float* be = bias + (size_t)e * N;
#pragma unroll
  for (int mi = 0; mi < 2; ++mi) {
#pragma unroll
    for (int reg = 0; reg < 16; ++reg) {
      int row = m0 + wm*64 + mi*32 + 4*khalf + (reg & 3) + 8*(reg >> 2);
      size_t rowoff = ((size_t)e * CAP + row) * N;
#pragma unroll
      for (int ni = 0; ni < 2; ++ni) {
        int col = blockIdx.x * BN + wn*64 + ni*32 + n31;
        float v = acc[mi][ni][reg] + be[col];
        if constexpr (GELU) v = fast_gelu(v);
        if constexpr (OUTF16) ((_Float16*)Cout)[rowoff + col] = (_Float16)v;
        else                  ((float*)Cout)[rowoff + col] = v;
      }
    }
  }
}

// ---------------- combine: out[t] = sum_k w_k * ybuf[slot_k] ----------------
__global__ __launch_bounds__(256) void combine_kernel(
    const float* __restrict__ ybuf, const int* __restrict__ assign_slot,
    const float* __restrict__ topk_w, float* __restrict__ out)
{
  int t = blockIdx.x;
  int s0 = assign_slot[t*2+0], s1 = assign_slot[t*2+1];
  float w0 = topk_w[t*2+0], w1 = topk_w[t*2+1];
  float4 a = {0.f, 0.f, 0.f, 0.f};
  int j = threadIdx.x;
  if (s0 >= 0) {
    float4 y = ((const float4*)(ybuf + (size_t)s0 * DM))[j];
    a.x += w0*y.x; a.y += w0*y.y; a.z += w0*y.z; a.w += w0*y.w;
  }
  if (s1 >= 0) {
    float4 y = ((const float4*)(ybuf + (size_t)s1 * DM))[j];
    a.x += w1*y.x; a.y += w1*y.y; a.z += w1*y.z; a.w += w1*y.w;
  }
  ((float4*)(out + (size_t)t * DM))[j] = a;
}

extern "C" void kernel_launch(void* const* d_in, const int* in_sizes, int n_in,
                              void* d_out, int out_size, void* d_ws, size_t ws_size,
                              hipStream_t stream)
{
  (void)in_sizes; (void)n_in; (void)out_size; (void)ws_size;
  const float* x  = (const float*)d_in[0];
  const float* Wr = (const float*)d_in[1];
  const float* br = (const float*)d_in[2];
  const float* W1 = (const float*)d_in[3];
  const float* b1 = (const float*)d_in[4];
  const float* W2 = (const float*)d_in[5];
  const float* b2 = (const float*)d_in[6];
  float* out = (float*)d_out;

  char* wsp = (char*)d_ws;
  size_t off = 0;
  auto take = [&](size_t bytes) { char* p = wsp + off; off += (bytes + 255) & ~(size_t)255; return p; };
  _Float16* W1t  = (_Float16*)take((size_t)NE * FF * DM * 2);   // [E][f][d]
  _Float16* W2t  = (_Float16*)take((size_t)NE * DM * FF * 2);   // [E][d][f]
  _Float16* xbuf = (_Float16*)take((size_t)NE * CAP * DM * 2);  // [E][cap][d]
  _Float16* hbuf = (_Float16*)take((size_t)NE * CAP * FF * 2);  // [E][cap][f]
  float*    ybuf = (float*)take((size_t)NE * CAP * DM * 4);     // [E][cap][d]
  int*   topk_e      = (int*)take((size_t)T_TOK * KTOP * 4);
  float* topk_w      = (float*)take((size_t)T_TOK * KTOP * 4);
  int*   assign_slot = (int*)take((size_t)T_TOK * KTOP * 4);
  int*   slot_token  = (int*)take((size_t)NE * CAP * 4);
  int*   counts      = (int*)take((size_t)NE * 4);
  int*   hist        = (int*)take((size_t)NCHUNK * NE * 4);
  int*   cbase       = (int*)take((size_t)NCHUNK * NE * 4);

  router_kernel<<<T_TOK / 4, 256, 0, stream>>>(x, Wr, br, topk_e, topk_w);
  hist_kernel<<<NCHUNK, 256, 0, stream>>>(topk_e, hist);
  prefix_kernel<<<1, 64, 0, stream>>>(hist, cbase, counts);
  assign_kernel<<<NCHUNK, 256, 0, stream>>>(topk_e, cbase, assign_slot, slot_token);
  transpose_f16<<<dim3(FF/64, DM/64, NE), 256, 0, stream>>>(W1, W1t, DM, FF);
  transpose_f16<<<dim3(DM/64, FF/64, NE), 256, 0, stream>>>(W2, W2t, FF, DM);
  gather_kernel<<<dim3(CAP, NE), 256, 0, stream>>>(x, slot_token, counts, xbuf);
  gemm_bt<true,  true ><<<dim3(FF/128, CAP/128, NE), 256, 0, stream>>>(xbuf, W1t, b1, (void*)hbuf, counts, DM, FF);
  gemm_bt<false, false><<<dim3(DM/128, CAP/128, NE), 256, 0, stream>>>(hbuf, W2t, b2, (void*)ybuf, counts, FF, DM);
  combine_kernel<<<T_TOK, 256, 0, stream>>>(ybuf, assign_slot, topk_w, out);
}